// Round 8
// baseline (473.995 us; speedup 1.0000x reference)
//
#include <hip/hip_runtime.h>
#include <hip/hip_bf16.h>
#include <stdint.h>

#define LL 1024
#define BB 256
#define CC 96
#define HH 768
#define NW 9216   // CC*CC
#define NTOT 9408 // NW + 2*CC
#define SEGS 8
#define SEGLEN 128
#define CHPB 15   // chain slots per batch: 8 fw + 7 bw

typedef __attribute__((ext_vector_type(4))) float floatx4;
typedef __attribute__((ext_vector_type(2))) float floatx2;
typedef __attribute__((ext_vector_type(8))) short short8;

#define KAPPA 0x1p-16f
#define NEG_LOG_KAPPA 11.090354888959125f  // 16*ln2

__device__ __forceinline__ unsigned short f2bf(float f) {
  uint32_t u = __float_as_uint(f);
  return (unsigned short)((u + 0x7FFFu + ((u >> 16) & 1u)) >> 16);
}

// ---------------- fused bf16 MFMA GEMM: out = hidden @ [Wt;Ws;We]^T + bias ---
#define GA_LD 40

__global__ __launch_bounds__(256) void gemm_mfma(
    const float* __restrict__ hidden, const float* __restrict__ Wt,
    const float* __restrict__ Ws, const float* __restrict__ We,
    const float* __restrict__ bt, const float* __restrict__ bs,
    const float* __restrict__ be, float* __restrict__ trans,
    float* __restrict__ tstart, float* __restrict__ tend) {
  __shared__ __align__(16) unsigned short As[128 * GA_LD];
  __shared__ __align__(16) unsigned short Bs[128 * GA_LD];
  const int t = threadIdx.x;
  const int lane = t & 63, wid = t >> 6;
  const int wm = wid >> 1, wn = wid & 1;
  const int l15 = lane & 15, qd = lane >> 4;
  const int m0 = blockIdx.y * 128, n0 = blockIdx.x * 128;
  const int srow = t >> 1, shalf = t & 1;

  floatx4 acc[4][4];
#pragma unroll
  for (int i = 0; i < 4; ++i)
#pragma unroll
    for (int j = 0; j < 4; ++j) acc[i][j] = (floatx4){0.f, 0.f, 0.f, 0.f};

  const int r = n0 + srow;
  const float* bsrc = (r < NW)        ? Wt + (size_t)r * HH
                      : (r < NW + CC) ? Ws + (size_t)(r - NW) * HH
                      : (r < NTOT)    ? We + (size_t)(r - NW - CC) * HH
                                      : nullptr;
  const float* asrc = hidden + (size_t)(m0 + srow) * HH;
  const int sidx = srow * GA_LD + shalf * 16;

  for (int k0 = 0; k0 < HH; k0 += 32) {
    __syncthreads();
    {
      const float4* s4 = (const float4*)(asrc + k0 + shalf * 16);
      uint32_t w[8];
#pragma unroll
      for (int u = 0; u < 4; ++u) {
        float4 v = s4[u];
        w[2 * u] = (uint32_t)f2bf(v.x) | ((uint32_t)f2bf(v.y) << 16);
        w[2 * u + 1] = (uint32_t)f2bf(v.z) | ((uint32_t)f2bf(v.w) << 16);
      }
      *(uint4*)&As[sidx] = make_uint4(w[0], w[1], w[2], w[3]);
      *(uint4*)&As[sidx + 8] = make_uint4(w[4], w[5], w[6], w[7]);
    }
    {
      uint32_t w[8];
      if (bsrc) {
        const float4* s4 = (const float4*)(bsrc + k0 + shalf * 16);
#pragma unroll
        for (int u = 0; u < 4; ++u) {
          float4 v = s4[u];
          w[2 * u] = (uint32_t)f2bf(v.x) | ((uint32_t)f2bf(v.y) << 16);
          w[2 * u + 1] = (uint32_t)f2bf(v.z) | ((uint32_t)f2bf(v.w) << 16);
        }
      } else {
#pragma unroll
        for (int u = 0; u < 8; ++u) w[u] = 0u;
      }
      *(uint4*)&Bs[sidx] = make_uint4(w[0], w[1], w[2], w[3]);
      *(uint4*)&Bs[sidx + 8] = make_uint4(w[4], w[5], w[6], w[7]);
    }
    __syncthreads();
    short8 af[4], bf[4];
#pragma unroll
    for (int i = 0; i < 4; ++i)
      af[i] = *(const short8*)&As[(64 * wm + 16 * i + l15) * GA_LD + qd * 8];
#pragma unroll
    for (int j = 0; j < 4; ++j)
      bf[j] = *(const short8*)&Bs[(64 * wn + 16 * j + l15) * GA_LD + qd * 8];
#pragma unroll
    for (int i = 0; i < 4; ++i)
#pragma unroll
      for (int j = 0; j < 4; ++j)
        acc[i][j] = __builtin_amdgcn_mfma_f32_16x16x32_bf16(af[i], bf[j],
                                                            acc[i][j], 0, 0, 0);
  }

#pragma unroll
  for (int j = 0; j < 4; ++j) {
    int n = n0 + 64 * wn + 16 * j + l15;
    if (n >= NTOT) continue;
    float bv;
    float* dst;
    int ldo;
    if (n < NW) {
      bv = bt[n]; dst = trans + n; ldo = NW;
    } else if (n < NW + CC) {
      bv = bs[n - NW]; dst = tstart + (n - NW); ldo = CC;
    } else {
      bv = be[n - NW - CC]; dst = tend + (n - NW - CC); ldo = CC;
    }
#pragma unroll
    for (int i = 0; i < 4; ++i)
#pragma unroll
      for (int rr = 0; rr < 4; ++rr) {
        int m = m0 + 64 * wm + 16 * i + 4 * qd + rr;
        dst[(size_t)m * ldo] = acc[i][j][rr] + bv;
      }
  }
}

// ---------------- helpers --------------------------------------------------
__device__ __forceinline__ float wredf(float v) {
#pragma unroll
  for (int m = 32; m >= 1; m >>= 1) v += __shfl_xor(v, m);
  return v;
}
__device__ __forceinline__ int wredi(int v) {
#pragma unroll
  for (int m = 32; m >= 1; m >>= 1) v += __shfl_xor(v, m);
  return v;
}
__device__ __forceinline__ float bcast0(float x) {
  return __uint_as_float(__builtin_amdgcn_readfirstlane(__float_as_uint(x)));
}
// quad sum via DPP (pure VALU: keeps the DS pipe clear).
__device__ __forceinline__ float qsum4(float x) {
  x += __int_as_float(__builtin_amdgcn_mov_dpp(__float_as_int(x), 0xB1, 0xF, 0xF, false));
  x += __int_as_float(__builtin_amdgcn_mov_dpp(__float_as_int(x), 0x4E, 0xF, 0xF, false));
  return x;
}
__device__ __forceinline__ int get_len(const void* mask, int b, int l) {
  int cnt = 0;
  unsigned w0 = *(const unsigned*)mask;
  if (w0 == 1u) {
    const int* m32 = (const int*)mask;
    for (int i = l; i < LL; i += 64) cnt += (m32[i * BB + b] != 0);
  } else if (w0 == 0x01010101u) {
    const unsigned char* m8 = (const unsigned char*)mask;
    for (int i = l; i < LL; i += 64) cnt += (m8[i * BB + b] != 0);
  } else {
    const float* mf = (const float*)mask;
    for (int i = l; i < LL; i += 64) cnt += (mf[i * BB + b] != 0.f);
  }
  return wredi(cnt);
}

// ---------------- segment chain kernel: 2048 blocks x 1 wave ----------------
// FUSED dual-chain waves (R6 retry with explicit source-level fusion):
// two same-direction segments of one batch share the T2 register slice;
// each step loads BOTH u-slices (12 b128 issued together), runs ONE fused
// FMA loop over both accumulator sets, then both E-reads/writes. At the
// measured 1 wave/SIMD residency cap (R0-R7), the full 512-reg budget is
// available, so chain B's state is free; its issue fills chain A's ~700cy
// LDS-dependency stall. Pairing is ADJACENT (lower seg of an active pair
// is provably full => nearly all steps paired):
//   blk = b*8+k. k<4: fw pair (2k,2k+1). k=4..6: bw pair (2(k-4)+1,+2).
//   k=7: bw solo seg 7. Slots: fw seg s -> s, bw seg s -> 7+s.
// Per-chain math is bit-identical to the R7 SPLIT=4 kernel.
__global__ __launch_bounds__(64, 1) void crf_chain(
    const float* __restrict__ emit, const void* __restrict__ mask,
    const float* __restrict__ trans, const float* __restrict__ tstart,
    float* __restrict__ xvec, float* __restrict__ lsc) {
  const int blk = blockIdx.x;
  const int b = blk >> 3;
  const int k = blk & 7;
  const bool isfw = (k < 4);
  int segA, segB = 0;
  bool hasB;
  if (isfw) { segA = 2 * k; segB = 2 * k + 1; hasB = true; }
  else if (k < 7) { segA = 2 * (k - 4) + 1; segB = segA + 1; hasB = true; }
  else { segA = 7; hasB = false; }
  const int l = threadIdx.x;
  const int g = l >> 2, q = l & 3;

  __shared__ __align__(16) float ebA[2][8][CC];
  __shared__ __align__(16) float uA[CC];
  __shared__ __align__(16) float ebB[2][8][CC];
  __shared__ __align__(16) float uB[CC];

  const int len = get_len(mask, b, l);
  const int loA = segA * SEGLEN + 1;
  const int hiA = min((segA + 1) * SEGLEN, len - 1);
  const int loB = hasB ? segB * SEGLEN + 1 : 0;
  const int hiB = hasB ? min((segB + 1) * SEGLEN, len - 1) : -1;
  const bool actA = hiA >= loA;
  const bool actB = hasB && (hiB >= loB);
  const int cidA = b * CHPB + (isfw ? segA : 7 + segA);
  const int cidB = hasB ? (b * CHPB + (isfw ? segB : 7 + segB)) : 0;

  if (hasB && !actB) {  // empty B -> identity
    float* xo = xvec + (size_t)cidB * CC;
    xo[l] = 1.f;
    if (l < 32) xo[l + 64] = 1.f;
    if (l == 0) lsc[cidB] = 0.f;
  }
  if (!actA) {  // actB => actA, so nothing left to do
    float* xo = xvec + (size_t)cidA * CC;
    xo[l] = 1.f;
    if (l < 32) xo[l + 64] = 1.f;
    if (l == 0) lsc[cidA] = 0.f;
    return;
  }
  const int nA = hiA - loA + 1;
  const int nB = actB ? (hiB - loB + 1) : 0;

  // ---- T registers (shared by both chains; direction-dependent slice) ----
  // fw: T2[t][m] = {expT[24q+2m][6g+t], expT[24q+2m+1][6g+t]}
  // bw: T2[t][m] = {expT[6g+t][24q+2m], expT[6g+t][24q+2m+1]}
  const float* tb = trans + (size_t)b * (CC * CC);
  floatx2 T2[6][12];
  if (isfw) {
#pragma unroll
    for (int t = 0; t < 6; ++t)
#pragma unroll
      for (int m = 0; m < 12; ++m) {
        const float* p0 = tb + (24 * q + 2 * m) * CC + 6 * g + t;
        T2[t][m] = (floatx2){__expf(p0[0]), __expf(p0[CC])};
      }
  } else {
#pragma unroll
    for (int t = 0; t < 6; ++t) {
      const float* row = tb + (6 * g + t) * CC + 24 * q;
#pragma unroll
      for (int m = 0; m < 12; ++m)
        T2[t][m] = (floatx2){__expf(row[2 * m]), __expf(row[2 * m + 1])};
    }
  }

  const float4* e4 = (const float4*)emit;
  const int eidx = 6 * g + 2 * (q < 3 ? q : 2);
  float LA = 0.f, pvA = 1.f, LB = 0.f, pvB = 1.f;

#define CLOB asm volatile("" ::: "memory")

#define STAGE_CHUNK(EB, baserow, slot)                                    \
  {                                                                       \
    _Pragma("unroll") for (int uu = 0; uu < 3; ++uu) {                    \
      int v = l + 64 * uu;                                                \
      int rw = v / 24, c4 = v - 24 * rw;                                  \
      float4 vv = e4[(((baserow) + rw) * BB + b) * 24 + c4];              \
      floatx4 o = {__expf(vv.x) * KAPPA, __expf(vv.y) * KAPPA,            \
                   __expf(vv.z) * KAPPA, __expf(vv.w) * KAPPA};           \
      *(floatx4*)&EB[slot][rw][c4 * 4] = o;                               \
    }                                                                     \
  }

  // solo DOT (identical math to R7)
#define INNER_DOT6(UU, aV)                                                \
  float aV[6];                                                            \
  {                                                                       \
    const floatx4* up_ = (const floatx4*)&UU[24 * q];                     \
    floatx4 R_[6];                                                        \
    _Pragma("unroll") for (int nn = 0; nn < 6; ++nn) R_[nn] = up_[nn];    \
    floatx2 P_[6], Q_[6];                                                 \
    _Pragma("unroll") for (int t = 0; t < 6; ++t) {                       \
      P_[t] = (floatx2){0.f, 0.f}; Q_[t] = (floatx2){0.f, 0.f};           \
    }                                                                     \
    _Pragma("unroll") for (int nn = 0; nn < 6; ++nn) {                    \
      floatx2 lo_ = {R_[nn].x, R_[nn].y}, hi_ = {R_[nn].z, R_[nn].w};     \
      _Pragma("unroll") for (int t = 0; t < 6; ++t) {                     \
        P_[t] += lo_ * T2[t][2 * nn]; Q_[t] += hi_ * T2[t][2 * nn + 1];   \
      }                                                                   \
    }                                                                     \
    _Pragma("unroll") for (int t = 0; t < 6; ++t) {                       \
      floatx2 S_ = P_[t] + Q_[t];                                         \
      aV[t] = qsum4(S_.x + S_.y);                                         \
    }                                                                     \
  }

  // fused dual DOT: both u-slices loaded first, one FMA loop for both
#define DUAL_DOT6(aAv, aBv)                                               \
  float aAv[6], aBv[6];                                                   \
  {                                                                       \
    const floatx4* upA_ = (const floatx4*)&uA[24 * q];                    \
    const floatx4* upB_ = (const floatx4*)&uB[24 * q];                    \
    floatx4 RA_[6], RB_[6];                                               \
    _Pragma("unroll") for (int nn = 0; nn < 6; ++nn) {                    \
      RA_[nn] = upA_[nn]; RB_[nn] = upB_[nn];                             \
    }                                                                     \
    floatx2 PA_[6], QA_[6], PB_[6], QB_[6];                               \
    _Pragma("unroll") for (int t = 0; t < 6; ++t) {                       \
      PA_[t] = (floatx2){0.f, 0.f}; QA_[t] = (floatx2){0.f, 0.f};         \
      PB_[t] = (floatx2){0.f, 0.f}; QB_[t] = (floatx2){0.f, 0.f};         \
    }                                                                     \
    _Pragma("unroll") for (int nn = 0; nn < 6; ++nn) {                    \
      floatx2 la_ = {RA_[nn].x, RA_[nn].y}, ha_ = {RA_[nn].z, RA_[nn].w}; \
      floatx2 lb_ = {RB_[nn].x, RB_[nn].y}, hb_ = {RB_[nn].z, RB_[nn].w}; \
      _Pragma("unroll") for (int t = 0; t < 6; ++t) {                     \
        PA_[t] += la_ * T2[t][2 * nn]; QA_[t] += ha_ * T2[t][2 * nn + 1]; \
        PB_[t] += lb_ * T2[t][2 * nn]; QB_[t] += hb_ * T2[t][2 * nn + 1]; \
      }                                                                   \
    }                                                                     \
    _Pragma("unroll") for (int t = 0; t < 6; ++t) {                       \
      floatx2 S_ = PA_[t] + QA_[t];                                       \
      aAv[t] = qsum4(S_.x + S_.y);                                        \
      S_ = PB_[t] + QB_[t];                                               \
      aBv[t] = qsum4(S_.x + S_.y);                                        \
    }                                                                     \
  }

#define WRITE_U(UU, aV, Ex_, Ey_, invP_)                                  \
  {                                                                       \
    float wx = (q == 0) ? aV[0] : ((q == 1) ? aV[2] : aV[4]);             \
    float wy = (q == 0) ? aV[1] : ((q == 1) ? aV[3] : aV[5]);             \
    if (q < 3) {                                                          \
      floatx2 wv = {wx * (Ex_) * (invP_), wy * (Ey_) * (invP_)};          \
      *(floatx2*)&UU[6 * g + 2 * q] = wv;                                 \
    }                                                                     \
  }

  if (isfw) {
    const int bA0 = loA & ~7;
    STAGE_CHUNK(ebA, bA0, (bA0 >> 3) & 1);
    if (actB) {
      const int bB0 = loB & ~7;
      STAGE_CHUNK(ebB, bB0, (bB0 >> 3) & 1);
    }
    if (segA == 0) {
      float a00 = emit[(size_t)b * CC] + tstart[b * CC];
      LA = a00;
      float v = emit[(size_t)b * CC + l] + tstart[b * CC + l];
      uA[l] = __expf(v - a00);
      if (l < 32) {
        int c2 = l + 64;
        float v2 = emit[(size_t)b * CC + c2] + tstart[b * CC + c2];
        uA[c2] = __expf(v2 - a00);
      }
    } else {
      uA[l] = 1.f;
      if (l < 32) uA[l + 64] = 1.f;
    }
    if (actB) {
      uB[l] = 1.f;
      if (l < 32) uB[l + 64] = 1.f;
    }
    CLOB;
    int jj = 1, iA = loA, iB = loB;
    for (; jj <= nB; ++jj, ++iA, ++iB) {  // paired steps
      bool st = false;
      if ((iA & 7) == 0) { STAGE_CHUNK(ebA, iA, (iA >> 3) & 1); st = true; }
      if ((iB & 7) == 0) { STAGE_CHUNK(ebB, iB, (iB >> 3) & 1); st = true; }
      if (st) CLOB;
      float invPA = 1.f, invPB = 1.f;
      if ((jj & 3) == 0) {
        invPA = 1.0f / pvA; LA += __logf(pvA);
        invPB = 1.0f / pvB; LB += __logf(pvB);
      }
      DUAL_DOT6(aA, aB);
      floatx2 EA = *(const floatx2*)&ebA[(iA >> 3) & 1][iA & 7][eidx];
      floatx2 EBv = *(const floatx2*)&ebB[(iB >> 3) & 1][iB & 7][eidx];
      float o0A = aA[0] * EA.x * invPA;
      float o0B = aB[0] * EBv.x * invPB;
      if (((jj + 1) & 3) == 0) { pvA = bcast0(o0A); pvB = bcast0(o0B); }
      WRITE_U(uA, aA, EA.x, EA.y, invPA);
      WRITE_U(uB, aB, EBv.x, EBv.y, invPB);
      CLOB;
    }
    for (; iA <= hiA; ++iA, ++jj) {  // A tail (solo)
      if ((iA & 7) == 0) { STAGE_CHUNK(ebA, iA, (iA >> 3) & 1); CLOB; }
      float invP = 1.f;
      if ((jj & 3) == 0) { invP = 1.0f / pvA; LA += __logf(pvA); }
      INNER_DOT6(uA, aS);
      floatx2 E = *(const floatx2*)&ebA[(iA >> 3) & 1][iA & 7][eidx];
      float o0 = aS[0] * E.x * invP;
      if (((jj + 1) & 3) == 0) pvA = bcast0(o0);
      WRITE_U(uA, aS, E.x, E.y, invP);
      CLOB;
    }
  } else {
    const int cA0 = hiA & ~7;
    STAGE_CHUNK(ebA, cA0, (cA0 >> 3) & 1);
    if (actB) {
      const int cB0 = hiB & ~7;
      STAGE_CHUNK(ebB, cB0, (cB0 >> 3) & 1);
    }
    CLOB;
    uA[l] = ebA[(hiA >> 3) & 1][hiA & 7][l];
    if (l < 32) uA[l + 64] = ebA[(hiA >> 3) & 1][hiA & 7][l + 64];
    if (actB) {
      uB[l] = ebB[(hiB >> 3) & 1][hiB & 7][l];
      if (l < 32) uB[l + 64] = ebB[(hiB >> 3) & 1][hiB & 7][l + 64];
    }
    CLOB;
    int jj = 1, iA = hiA, iB = hiB;
    for (; jj <= nB; ++jj, --iA, --iB) {  // paired steps
      bool st = false;
      if ((iA & 7) == 0 && iA > loA) {
        STAGE_CHUNK(ebA, iA - 8, ((iA >> 3) & 1) ^ 1); st = true;
      }
      if ((iB & 7) == 0 && iB > loB) {
        STAGE_CHUNK(ebB, iB - 8, ((iB >> 3) & 1) ^ 1); st = true;
      }
      if (st) CLOB;
      float invPA = 1.f, invPB = 1.f;
      if ((jj & 3) == 0) {
        invPA = 1.0f / pvA; LA += __logf(pvA);
        invPB = 1.0f / pvB; LB += __logf(pvB);
      }
      DUAL_DOT6(aA, aB);
      floatx2 EA = (iA > loA)
          ? *(const floatx2*)&ebA[((iA - 1) >> 3) & 1][(iA - 1) & 7][eidx]
          : (floatx2){1.f, 1.f};
      floatx2 EBv = (iB > loB)
          ? *(const floatx2*)&ebB[((iB - 1) >> 3) & 1][(iB - 1) & 7][eidx]
          : (floatx2){1.f, 1.f};
      float o0A = aA[0] * EA.x * invPA;
      float o0B = aB[0] * EBv.x * invPB;
      if (((jj + 1) & 3) == 0) { pvA = bcast0(o0A); pvB = bcast0(o0B); }
      WRITE_U(uA, aA, EA.x, EA.y, invPA);
      WRITE_U(uB, aB, EBv.x, EBv.y, invPB);
      CLOB;
    }
    for (; iA >= loA; --iA, ++jj) {  // A tail (solo)
      if ((iA & 7) == 0 && iA > loA) {
        STAGE_CHUNK(ebA, iA - 8, ((iA >> 3) & 1) ^ 1); CLOB;
      }
      float invP = 1.f;
      if ((jj & 3) == 0) { invP = 1.0f / pvA; LA += __logf(pvA); }
      INNER_DOT6(uA, aS);
      floatx2 E = (iA > loA)
          ? *(const floatx2*)&ebA[((iA - 1) >> 3) & 1][(iA - 1) & 7][eidx]
          : (floatx2){1.f, 1.f};
      float o0 = aS[0] * E.x * invP;
      if (((jj + 1) & 3) == 0) pvA = bcast0(o0);
      WRITE_U(uA, aS, E.x, E.y, invP);
      CLOB;
    }
  }

  CLOB;
  {
    float* xo = xvec + (size_t)cidA * CC;
    xo[l] = uA[l];
    if (l < 32) xo[l + 64] = uA[l + 64];
    if (l == 0) lsc[cidA] = LA + (float)nA * NEG_LOG_KAPPA;
  }
  if (actB) {
    float* xo = xvec + (size_t)cidB * CC;
    xo[l] = uB[l];
    if (l < 32) xo[l + 64] = uB[l + 64];
    if (l == 0) lsc[cidB] = LB + (float)nB * NEG_LOG_KAPPA;
  }
}

// ---------------- composition + score: 256 blocks x 1 wave ------------------
__global__ __launch_bounds__(64) void crf_compose(
    const float* __restrict__ emit, const int* __restrict__ target,
    const void* __restrict__ mask, const float* __restrict__ trans,
    const float* __restrict__ tstart, const float* __restrict__ tend,
    const float* __restrict__ xvec, const float* __restrict__ lsc,
    float* __restrict__ out) {
  const int b = blockIdx.x;
  const int l = threadIdx.x;
  const int len = get_len(mask, b, l);

  // telescope: x_s = a_s * e^{g_s} * (b_s . x_{s-1})/(b_s . 1)
  float Lam = lsc[b * CHPB + 0];
  const float* xcur = xvec + (size_t)(b * CHPB + 0) * CC;
  for (int s2 = 1; s2 < SEGS; ++s2) {
    if (s2 * SEGLEN + 1 > len - 1) break;  // empty segment = identity
    const float* bh = xvec + (size_t)(b * CHPB + (SEGS - 1) + s2) * CC;
    const float* ah = xvec + (size_t)(b * CHPB + s2) * CC;
    float pn = bh[l] * xcur[l];
    float pd = bh[l];
    if (l < 32) {
      pn += bh[l + 64] * xcur[l + 64];
      pd += bh[l + 64];
    }
    float num = wredf(pn), den = wredf(pd);
    Lam += __logf(num / den) + lsc[b * CHPB + s2];
    xcur = ah;
  }
  float zp = xcur[l] * __expf(tend[b * CC + l]);
  if (l < 32) zp += xcur[l + 64] * __expf(tend[b * CC + l + 64]);
  float logz = Lam + __logf(wredf(zp));

  // gold-path score
  const float* tb = trans + (size_t)b * (CC * CC);
  float sc = 0.f;
  for (int i = l; i < len; i += 64) {
    int tg = target[i * BB + b];
    sc += emit[((size_t)i * BB + b) * CC + tg];
    if (i >= 1) sc += tb[target[(i - 1) * BB + b] * CC + tg];
  }
  float score = wredf(sc);
  if (l == 0) {
    score += tstart[b * CC + target[b]] +
             tend[b * CC + target[(len - 1) * BB + b]];
    atomicAdd(out, (logz - score) * (1.0f / 256.0f));
  }
}

extern "C" void kernel_launch(void* const* d_in, const int* in_sizes, int n_in,
                              void* d_out, int out_size, void* d_ws, size_t ws_size,
                              hipStream_t stream) {
  const float* emit = (const float*)d_in[0];
  const float* hidden = (const float*)d_in[1];
  const int* target = (const int*)d_in[2];
  const void* mask = d_in[3];
  const float* Wt = (const float*)d_in[4];
  const float* bt = (const float*)d_in[5];
  const float* Ws = (const float*)d_in[6];
  const float* bs = (const float*)d_in[7];
  const float* We = (const float*)d_in[8];
  const float* be = (const float*)d_in[9];

  float* trans_ws = (float*)d_ws;                  // 256*9216
  float* ts_ws = trans_ws + (size_t)BB * CC * CC;  // 256*96
  float* te_ws = ts_ws + (size_t)BB * CC;          // 256*96
  float* xvec = te_ws + (size_t)BB * CC;           // 3840*96
  float* lsc = xvec + (size_t)BB * CHPB * CC;      // 3840

  hipMemsetAsync(d_out, 0, sizeof(float), stream);

  gemm_mfma<<<dim3((NTOT + 127) / 128, 2), 256, 0, stream>>>(
      hidden, Wt, Ws, We, bt, bs, be, trans_ws, ts_ws, te_ws);

  crf_chain<<<BB * 8, 64, 0, stream>>>(emit, mask, trans_ws, ts_ws, xvec, lsc);

  crf_compose<<<BB, 64, 0, stream>>>(emit, target, mask, trans_ws, ts_ws, te_ws,
                                     xvec, lsc, (float*)d_out);
}

// Round 9
// 405.224 us; speedup vs baseline: 1.1697x; 1.1697x over previous
//
#include <hip/hip_runtime.h>
#include <hip/hip_bf16.h>
#include <stdint.h>

#define LL 1024
#define BB 256
#define CC 96
#define HH 768
#define NW 9216   // CC*CC
#define NTOT 9408 // NW + 2*CC
#define SEGS 8
#define SEGLEN 128
#define CHPB 15   // chain slots per batch: 8 fw + 7 bw

typedef __attribute__((ext_vector_type(4))) float floatx4;
typedef __attribute__((ext_vector_type(2))) float floatx2;
typedef __attribute__((ext_vector_type(8))) short short8;

#define KAPPA 0x1p-16f
#define NEG_LOG_KAPPA 11.090354888959125f  // 16*ln2

__device__ __forceinline__ unsigned short f2bf(float f) {
  uint32_t u = __float_as_uint(f);
  return (unsigned short)((u + 0x7FFFu + ((u >> 16) & 1u)) >> 16);
}

// ---------------- fused bf16 MFMA GEMM: out = hidden @ [Wt;Ws;We]^T + bias ---
#define GA_LD 40

__global__ __launch_bounds__(256) void gemm_mfma(
    const float* __restrict__ hidden, const float* __restrict__ Wt,
    const float* __restrict__ Ws, const float* __restrict__ We,
    const float* __restrict__ bt, const float* __restrict__ bs,
    const float* __restrict__ be, float* __restrict__ trans,
    float* __restrict__ tstart, float* __restrict__ tend) {
  __shared__ __align__(16) unsigned short As[128 * GA_LD];
  __shared__ __align__(16) unsigned short Bs[128 * GA_LD];
  const int t = threadIdx.x;
  const int lane = t & 63, wid = t >> 6;
  const int wm = wid >> 1, wn = wid & 1;
  const int l15 = lane & 15, qd = lane >> 4;
  const int m0 = blockIdx.y * 128, n0 = blockIdx.x * 128;
  const int srow = t >> 1, shalf = t & 1;

  floatx4 acc[4][4];
#pragma unroll
  for (int i = 0; i < 4; ++i)
#pragma unroll
    for (int j = 0; j < 4; ++j) acc[i][j] = (floatx4){0.f, 0.f, 0.f, 0.f};

  const int r = n0 + srow;
  const float* bsrc = (r < NW)        ? Wt + (size_t)r * HH
                      : (r < NW + CC) ? Ws + (size_t)(r - NW) * HH
                      : (r < NTOT)    ? We + (size_t)(r - NW - CC) * HH
                                      : nullptr;
  const float* asrc = hidden + (size_t)(m0 + srow) * HH;
  const int sidx = srow * GA_LD + shalf * 16;

  for (int k0 = 0; k0 < HH; k0 += 32) {
    __syncthreads();
    {
      const float4* s4 = (const float4*)(asrc + k0 + shalf * 16);
      uint32_t w[8];
#pragma unroll
      for (int u = 0; u < 4; ++u) {
        float4 v = s4[u];
        w[2 * u] = (uint32_t)f2bf(v.x) | ((uint32_t)f2bf(v.y) << 16);
        w[2 * u + 1] = (uint32_t)f2bf(v.z) | ((uint32_t)f2bf(v.w) << 16);
      }
      *(uint4*)&As[sidx] = make_uint4(w[0], w[1], w[2], w[3]);
      *(uint4*)&As[sidx + 8] = make_uint4(w[4], w[5], w[6], w[7]);
    }
    {
      uint32_t w[8];
      if (bsrc) {
        const float4* s4 = (const float4*)(bsrc + k0 + shalf * 16);
#pragma unroll
        for (int u = 0; u < 4; ++u) {
          float4 v = s4[u];
          w[2 * u] = (uint32_t)f2bf(v.x) | ((uint32_t)f2bf(v.y) << 16);
          w[2 * u + 1] = (uint32_t)f2bf(v.z) | ((uint32_t)f2bf(v.w) << 16);
        }
      } else {
#pragma unroll
        for (int u = 0; u < 8; ++u) w[u] = 0u;
      }
      *(uint4*)&Bs[sidx] = make_uint4(w[0], w[1], w[2], w[3]);
      *(uint4*)&Bs[sidx + 8] = make_uint4(w[4], w[5], w[6], w[7]);
    }
    __syncthreads();
    short8 af[4], bf[4];
#pragma unroll
    for (int i = 0; i < 4; ++i)
      af[i] = *(const short8*)&As[(64 * wm + 16 * i + l15) * GA_LD + qd * 8];
#pragma unroll
    for (int j = 0; j < 4; ++j)
      bf[j] = *(const short8*)&Bs[(64 * wn + 16 * j + l15) * GA_LD + qd * 8];
#pragma unroll
    for (int i = 0; i < 4; ++i)
#pragma unroll
      for (int j = 0; j < 4; ++j)
        acc[i][j] = __builtin_amdgcn_mfma_f32_16x16x32_bf16(af[i], bf[j],
                                                            acc[i][j], 0, 0, 0);
  }

#pragma unroll
  for (int j = 0; j < 4; ++j) {
    int n = n0 + 64 * wn + 16 * j + l15;
    if (n >= NTOT) continue;
    float bv;
    float* dst;
    int ldo;
    if (n < NW) {
      bv = bt[n]; dst = trans + n; ldo = NW;
    } else if (n < NW + CC) {
      bv = bs[n - NW]; dst = tstart + (n - NW); ldo = CC;
    } else {
      bv = be[n - NW - CC]; dst = tend + (n - NW - CC); ldo = CC;
    }
#pragma unroll
    for (int i = 0; i < 4; ++i)
#pragma unroll
      for (int rr = 0; rr < 4; ++rr) {
        int m = m0 + 64 * wm + 16 * i + 4 * qd + rr;
        dst[(size_t)m * ldo] = acc[i][j][rr] + bv;
      }
  }
}

// ---------------- helpers --------------------------------------------------
__device__ __forceinline__ float wredf(float v) {
#pragma unroll
  for (int m = 32; m >= 1; m >>= 1) v += __shfl_xor(v, m);
  return v;
}
__device__ __forceinline__ int wredi(int v) {
#pragma unroll
  for (int m = 32; m >= 1; m >>= 1) v += __shfl_xor(v, m);
  return v;
}
__device__ __forceinline__ float bcast0(float x) {
  return __uint_as_float(__builtin_amdgcn_readfirstlane(__float_as_uint(x)));
}
// quad sum via DPP (pure VALU: keeps the DS pipe clear).
__device__ __forceinline__ float qsum4(float x) {
  x += __int_as_float(__builtin_amdgcn_mov_dpp(__float_as_int(x), 0xB1, 0xF, 0xF, false));
  x += __int_as_float(__builtin_amdgcn_mov_dpp(__float_as_int(x), 0x4E, 0xF, 0xF, false));
  return x;
}
__device__ __forceinline__ int get_len(const void* mask, int b, int l) {
  int cnt = 0;
  unsigned w0 = *(const unsigned*)mask;
  if (w0 == 1u) {
    const int* m32 = (const int*)mask;
    for (int i = l; i < LL; i += 64) cnt += (m32[i * BB + b] != 0);
  } else if (w0 == 0x01010101u) {
    const unsigned char* m8 = (const unsigned char*)mask;
    for (int i = l; i < LL; i += 64) cnt += (m8[i * BB + b] != 0);
  } else {
    const float* mf = (const float*)mask;
    for (int i = l; i < LL; i += 64) cnt += (mf[i * BB + b] != 0.f);
  }
  return wredi(cnt);
}

// ---------------- segment chain kernel: 2048 blocks x 1 wave ----------------
// FUSED dual-chain (R8) + register diet:
//  - merged P/Q accumulators (one floatx2 per tag per chain): -24 regs
//  - u-loads in 2 batches of 3+3 b128 (A and B interleaved): -24 transient
//  - __launch_bounds__(64,2): allocator targets combined <=256 unified regs
//    so the HW can hold 2 waves/SIMD (the R0-R8 ledger: <=256 -> 2/SIMD,
//    >256 -> 1/SIMD; R8's 140+144=284 collapsed residency to ~2.4/CU).
// R8 measured the fused pair-step at ~1.33x a solo step (84us per wave for
// 2 chains vs 63us solo) -- this round keeps that and restores residency.
// blk = b*8+k. k<4: fw pair (2k,2k+1). k=4..6: bw pair (2(k-4)+1,+2).
// k=7: bw solo seg 7. Slots: fw seg s -> s, bw seg s -> 7+s.
__global__ __launch_bounds__(64, 2) void crf_chain(
    const float* __restrict__ emit, const void* __restrict__ mask,
    const float* __restrict__ trans, const float* __restrict__ tstart,
    float* __restrict__ xvec, float* __restrict__ lsc) {
  const int blk = blockIdx.x;
  const int b = blk >> 3;
  const int k = blk & 7;
  const bool isfw = (k < 4);
  int segA, segB = 0;
  bool hasB;
  if (isfw) { segA = 2 * k; segB = 2 * k + 1; hasB = true; }
  else if (k < 7) { segA = 2 * (k - 4) + 1; segB = segA + 1; hasB = true; }
  else { segA = 7; hasB = false; }
  const int l = threadIdx.x;
  const int g = l >> 2, q = l & 3;

  __shared__ __align__(16) float ebA[2][8][CC];
  __shared__ __align__(16) float uA[CC];
  __shared__ __align__(16) float ebB[2][8][CC];
  __shared__ __align__(16) float uB[CC];

  const int len = get_len(mask, b, l);
  const int loA = segA * SEGLEN + 1;
  const int hiA = min((segA + 1) * SEGLEN, len - 1);
  const int loB = hasB ? segB * SEGLEN + 1 : 0;
  const int hiB = hasB ? min((segB + 1) * SEGLEN, len - 1) : -1;
  const bool actA = hiA >= loA;
  const bool actB = hasB && (hiB >= loB);
  const int cidA = b * CHPB + (isfw ? segA : 7 + segA);
  const int cidB = hasB ? (b * CHPB + (isfw ? segB : 7 + segB)) : 0;

  if (hasB && !actB) {  // empty B -> identity
    float* xo = xvec + (size_t)cidB * CC;
    xo[l] = 1.f;
    if (l < 32) xo[l + 64] = 1.f;
    if (l == 0) lsc[cidB] = 0.f;
  }
  if (!actA) {  // actB => actA, so nothing left to do
    float* xo = xvec + (size_t)cidA * CC;
    xo[l] = 1.f;
    if (l < 32) xo[l + 64] = 1.f;
    if (l == 0) lsc[cidA] = 0.f;
    return;
  }
  const int nA = hiA - loA + 1;
  const int nB = actB ? (hiB - loB + 1) : 0;

  // ---- T registers (shared by both chains; direction-dependent slice) ----
  // fw: T2[t][m] = {expT[24q+2m][6g+t], expT[24q+2m+1][6g+t]}
  // bw: T2[t][m] = {expT[6g+t][24q+2m], expT[6g+t][24q+2m+1]}
  const float* tb = trans + (size_t)b * (CC * CC);
  floatx2 T2[6][12];
  if (isfw) {
#pragma unroll
    for (int t = 0; t < 6; ++t)
#pragma unroll
      for (int m = 0; m < 12; ++m) {
        const float* p0 = tb + (24 * q + 2 * m) * CC + 6 * g + t;
        T2[t][m] = (floatx2){__expf(p0[0]), __expf(p0[CC])};
      }
  } else {
#pragma unroll
    for (int t = 0; t < 6; ++t) {
      const float* row = tb + (6 * g + t) * CC + 24 * q;
#pragma unroll
      for (int m = 0; m < 12; ++m)
        T2[t][m] = (floatx2){__expf(row[2 * m]), __expf(row[2 * m + 1])};
    }
  }

  const float4* e4 = (const float4*)emit;
  const int eidx = 6 * g + 2 * (q < 3 ? q : 2);
  float LA = 0.f, pvA = 1.f, LB = 0.f, pvB = 1.f;

#define CLOB asm volatile("" ::: "memory")

#define STAGE_CHUNK(EB, baserow, slot)                                    \
  {                                                                       \
    _Pragma("unroll") for (int uu = 0; uu < 3; ++uu) {                    \
      int v = l + 64 * uu;                                                \
      int rw = v / 24, c4 = v - 24 * rw;                                  \
      float4 vv = e4[(((baserow) + rw) * BB + b) * 24 + c4];              \
      floatx4 o = {__expf(vv.x) * KAPPA, __expf(vv.y) * KAPPA,            \
                   __expf(vv.z) * KAPPA, __expf(vv.w) * KAPPA};           \
      *(floatx4*)&EB[slot][rw][c4 * 4] = o;                               \
    }                                                                     \
  }

  // solo DOT: merged accumulator (one floatx2 per tag), 2 load batches
#define INNER_DOT6(UU, aV)                                                \
  float aV[6];                                                            \
  {                                                                       \
    const floatx4* up_ = (const floatx4*)&UU[24 * q];                     \
    floatx2 C_[6];                                                        \
    _Pragma("unroll") for (int t = 0; t < 6; ++t) C_[t] = (floatx2){0.f, 0.f}; \
    _Pragma("unroll") for (int h = 0; h < 2; ++h) {                       \
      floatx4 R0_ = up_[3 * h], R1_ = up_[3 * h + 1], R2_ = up_[3 * h + 2]; \
      floatx2 l0_ = {R0_.x, R0_.y}, h0_ = {R0_.z, R0_.w};                 \
      floatx2 l1_ = {R1_.x, R1_.y}, h1_ = {R1_.z, R1_.w};                 \
      floatx2 l2_ = {R2_.x, R2_.y}, h2_ = {R2_.z, R2_.w};                 \
      _Pragma("unroll") for (int t = 0; t < 6; ++t) {                     \
        C_[t] += l0_ * T2[t][6 * h];     C_[t] += h0_ * T2[t][6 * h + 1]; \
        C_[t] += l1_ * T2[t][6 * h + 2]; C_[t] += h1_ * T2[t][6 * h + 3]; \
        C_[t] += l2_ * T2[t][6 * h + 4]; C_[t] += h2_ * T2[t][6 * h + 5]; \
      }                                                                   \
    }                                                                     \
    _Pragma("unroll") for (int t = 0; t < 6; ++t)                         \
      aV[t] = qsum4(C_[t].x + C_[t].y);                                   \
  }

  // fused dual DOT: A and B interleaved, 2 load batches of 3+3 b128
#define DUAL_DOT6(aAv, aBv)                                               \
  float aAv[6], aBv[6];                                                   \
  {                                                                       \
    const floatx4* upA_ = (const floatx4*)&uA[24 * q];                    \
    const floatx4* upB_ = (const floatx4*)&uB[24 * q];                    \
    floatx2 CA_[6], CB_[6];                                               \
    _Pragma("unroll") for (int t = 0; t < 6; ++t) {                       \
      CA_[t] = (floatx2){0.f, 0.f}; CB_[t] = (floatx2){0.f, 0.f};         \
    }                                                                     \
    _Pragma("unroll") for (int h = 0; h < 2; ++h) {                       \
      floatx4 RA0_ = upA_[3 * h], RA1_ = upA_[3 * h + 1], RA2_ = upA_[3 * h + 2]; \
      floatx4 RB0_ = upB_[3 * h], RB1_ = upB_[3 * h + 1], RB2_ = upB_[3 * h + 2]; \
      floatx2 la0_ = {RA0_.x, RA0_.y}, ha0_ = {RA0_.z, RA0_.w};           \
      floatx2 la1_ = {RA1_.x, RA1_.y}, ha1_ = {RA1_.z, RA1_.w};           \
      floatx2 la2_ = {RA2_.x, RA2_.y}, ha2_ = {RA2_.z, RA2_.w};           \
      floatx2 lb0_ = {RB0_.x, RB0_.y}, hb0_ = {RB0_.z, RB0_.w};           \
      floatx2 lb1_ = {RB1_.x, RB1_.y}, hb1_ = {RB1_.z, RB1_.w};           \
      floatx2 lb2_ = {RB2_.x, RB2_.y}, hb2_ = {RB2_.z, RB2_.w};           \
      _Pragma("unroll") for (int t = 0; t < 6; ++t) {                     \
        CA_[t] += la0_ * T2[t][6 * h];     CB_[t] += lb0_ * T2[t][6 * h]; \
        CA_[t] += ha0_ * T2[t][6 * h + 1]; CB_[t] += hb0_ * T2[t][6 * h + 1]; \
        CA_[t] += la1_ * T2[t][6 * h + 2]; CB_[t] += lb1_ * T2[t][6 * h + 2]; \
        CA_[t] += ha1_ * T2[t][6 * h + 3]; CB_[t] += hb1_ * T2[t][6 * h + 3]; \
        CA_[t] += la2_ * T2[t][6 * h + 4]; CB_[t] += lb2_ * T2[t][6 * h + 4]; \
        CA_[t] += ha2_ * T2[t][6 * h + 5]; CB_[t] += hb2_ * T2[t][6 * h + 5]; \
      }                                                                   \
    }                                                                     \
    _Pragma("unroll") for (int t = 0; t < 6; ++t) {                       \
      aAv[t] = qsum4(CA_[t].x + CA_[t].y);                                \
      aBv[t] = qsum4(CB_[t].x + CB_[t].y);                                \
    }                                                                     \
  }

#define WRITE_U(UU, aV, Ex_, Ey_, invP_)                                  \
  {                                                                       \
    float wx = (q == 0) ? aV[0] : ((q == 1) ? aV[2] : aV[4]);             \
    float wy = (q == 0) ? aV[1] : ((q == 1) ? aV[3] : aV[5]);             \
    if (q < 3) {                                                          \
      floatx2 wv = {wx * (Ex_) * (invP_), wy * (Ey_) * (invP_)};          \
      *(floatx2*)&UU[6 * g + 2 * q] = wv;                                 \
    }                                                                     \
  }

  if (isfw) {
    const int bA0 = loA & ~7;
    STAGE_CHUNK(ebA, bA0, (bA0 >> 3) & 1);
    if (actB) {
      const int bB0 = loB & ~7;
      STAGE_CHUNK(ebB, bB0, (bB0 >> 3) & 1);
    }
    if (segA == 0) {
      float a00 = emit[(size_t)b * CC] + tstart[b * CC];
      LA = a00;
      float v = emit[(size_t)b * CC + l] + tstart[b * CC + l];
      uA[l] = __expf(v - a00);
      if (l < 32) {
        int c2 = l + 64;
        float v2 = emit[(size_t)b * CC + c2] + tstart[b * CC + c2];
        uA[c2] = __expf(v2 - a00);
      }
    } else {
      uA[l] = 1.f;
      if (l < 32) uA[l + 64] = 1.f;
    }
    if (actB) {
      uB[l] = 1.f;
      if (l < 32) uB[l + 64] = 1.f;
    }
    CLOB;
    int jj = 1, iA = loA, iB = loB;
    for (; jj <= nB; ++jj, ++iA, ++iB) {  // paired steps
      bool st = false;
      if ((iA & 7) == 0) { STAGE_CHUNK(ebA, iA, (iA >> 3) & 1); st = true; }
      if ((iB & 7) == 0) { STAGE_CHUNK(ebB, iB, (iB >> 3) & 1); st = true; }
      if (st) CLOB;
      float invPA = 1.f, invPB = 1.f;
      if ((jj & 3) == 0) {
        invPA = 1.0f / pvA; LA += __logf(pvA);
        invPB = 1.0f / pvB; LB += __logf(pvB);
      }
      DUAL_DOT6(aA, aB);
      floatx2 EA = *(const floatx2*)&ebA[(iA >> 3) & 1][iA & 7][eidx];
      floatx2 EBv = *(const floatx2*)&ebB[(iB >> 3) & 1][iB & 7][eidx];
      float o0A = aA[0] * EA.x * invPA;
      float o0B = aB[0] * EBv.x * invPB;
      if (((jj + 1) & 3) == 0) { pvA = bcast0(o0A); pvB = bcast0(o0B); }
      WRITE_U(uA, aA, EA.x, EA.y, invPA);
      WRITE_U(uB, aB, EBv.x, EBv.y, invPB);
      CLOB;
    }
    for (; iA <= hiA; ++iA, ++jj) {  // A tail (solo)
      if ((iA & 7) == 0) { STAGE_CHUNK(ebA, iA, (iA >> 3) & 1); CLOB; }
      float invP = 1.f;
      if ((jj & 3) == 0) { invP = 1.0f / pvA; LA += __logf(pvA); }
      INNER_DOT6(uA, aS);
      floatx2 E = *(const floatx2*)&ebA[(iA >> 3) & 1][iA & 7][eidx];
      float o0 = aS[0] * E.x * invP;
      if (((jj + 1) & 3) == 0) pvA = bcast0(o0);
      WRITE_U(uA, aS, E.x, E.y, invP);
      CLOB;
    }
  } else {
    const int cA0 = hiA & ~7;
    STAGE_CHUNK(ebA, cA0, (cA0 >> 3) & 1);
    if (actB) {
      const int cB0 = hiB & ~7;
      STAGE_CHUNK(ebB, cB0, (cB0 >> 3) & 1);
    }
    CLOB;
    uA[l] = ebA[(hiA >> 3) & 1][hiA & 7][l];
    if (l < 32) uA[l + 64] = ebA[(hiA >> 3) & 1][hiA & 7][l + 64];
    if (actB) {
      uB[l] = ebB[(hiB >> 3) & 1][hiB & 7][l];
      if (l < 32) uB[l + 64] = ebB[(hiB >> 3) & 1][hiB & 7][l + 64];
    }
    CLOB;
    int jj = 1, iA = hiA, iB = hiB;
    for (; jj <= nB; ++jj, --iA, --iB) {  // paired steps
      bool st = false;
      if ((iA & 7) == 0 && iA > loA) {
        STAGE_CHUNK(ebA, iA - 8, ((iA >> 3) & 1) ^ 1); st = true;
      }
      if ((iB & 7) == 0 && iB > loB) {
        STAGE_CHUNK(ebB, iB - 8, ((iB >> 3) & 1) ^ 1); st = true;
      }
      if (st) CLOB;
      float invPA = 1.f, invPB = 1.f;
      if ((jj & 3) == 0) {
        invPA = 1.0f / pvA; LA += __logf(pvA);
        invPB = 1.0f / pvB; LB += __logf(pvB);
      }
      DUAL_DOT6(aA, aB);
      floatx2 EA = (iA > loA)
          ? *(const floatx2*)&ebA[((iA - 1) >> 3) & 1][(iA - 1) & 7][eidx]
          : (floatx2){1.f, 1.f};
      floatx2 EBv = (iB > loB)
          ? *(const floatx2*)&ebB[((iB - 1) >> 3) & 1][(iB - 1) & 7][eidx]
          : (floatx2){1.f, 1.f};
      float o0A = aA[0] * EA.x * invPA;
      float o0B = aB[0] * EBv.x * invPB;
      if (((jj + 1) & 3) == 0) { pvA = bcast0(o0A); pvB = bcast0(o0B); }
      WRITE_U(uA, aA, EA.x, EA.y, invPA);
      WRITE_U(uB, aB, EBv.x, EBv.y, invPB);
      CLOB;
    }
    for (; iA >= loA; --iA, ++jj) {  // A tail (solo)
      if ((iA & 7) == 0 && iA > loA) {
        STAGE_CHUNK(ebA, iA - 8, ((iA >> 3) & 1) ^ 1); CLOB;
      }
      float invP = 1.f;
      if ((jj & 3) == 0) { invP = 1.0f / pvA; LA += __logf(pvA); }
      INNER_DOT6(uA, aS);
      floatx2 E = (iA > loA)
          ? *(const floatx2*)&ebA[((iA - 1) >> 3) & 1][(iA - 1) & 7][eidx]
          : (floatx2){1.f, 1.f};
      float o0 = aS[0] * E.x * invP;
      if (((jj + 1) & 3) == 0) pvA = bcast0(o0);
      WRITE_U(uA, aS, E.x, E.y, invP);
      CLOB;
    }
  }

  CLOB;
  {
    float* xo = xvec + (size_t)cidA * CC;
    xo[l] = uA[l];
    if (l < 32) xo[l + 64] = uA[l + 64];
    if (l == 0) lsc[cidA] = LA + (float)nA * NEG_LOG_KAPPA;
  }
  if (actB) {
    float* xo = xvec + (size_t)cidB * CC;
    xo[l] = uB[l];
    if (l < 32) xo[l + 64] = uB[l + 64];
    if (l == 0) lsc[cidB] = LB + (float)nB * NEG_LOG_KAPPA;
  }
}

// ---------------- composition + score: 256 blocks x 1 wave ------------------
__global__ __launch_bounds__(64) void crf_compose(
    const float* __restrict__ emit, const int* __restrict__ target,
    const void* __restrict__ mask, const float* __restrict__ trans,
    const float* __restrict__ tstart, const float* __restrict__ tend,
    const float* __restrict__ xvec, const float* __restrict__ lsc,
    float* __restrict__ out) {
  const int b = blockIdx.x;
  const int l = threadIdx.x;
  const int len = get_len(mask, b, l);

  // telescope: x_s = a_s * e^{g_s} * (b_s . x_{s-1})/(b_s . 1)
  float Lam = lsc[b * CHPB + 0];
  const float* xcur = xvec + (size_t)(b * CHPB + 0) * CC;
  for (int s2 = 1; s2 < SEGS; ++s2) {
    if (s2 * SEGLEN + 1 > len - 1) break;  // empty segment = identity
    const float* bh = xvec + (size_t)(b * CHPB + (SEGS - 1) + s2) * CC;
    const float* ah = xvec + (size_t)(b * CHPB + s2) * CC;
    float pn = bh[l] * xcur[l];
    float pd = bh[l];
    if (l < 32) {
      pn += bh[l + 64] * xcur[l + 64];
      pd += bh[l + 64];
    }
    float num = wredf(pn), den = wredf(pd);
    Lam += __logf(num / den) + lsc[b * CHPB + s2];
    xcur = ah;
  }
  float zp = xcur[l] * __expf(tend[b * CC + l]);
  if (l < 32) zp += xcur[l + 64] * __expf(tend[b * CC + l + 64]);
  float logz = Lam + __logf(wredf(zp));

  // gold-path score
  const float* tb = trans + (size_t)b * (CC * CC);
  float sc = 0.f;
  for (int i = l; i < len; i += 64) {
    int tg = target[i * BB + b];
    sc += emit[((size_t)i * BB + b) * CC + tg];
    if (i >= 1) sc += tb[target[(i - 1) * BB + b] * CC + tg];
  }
  float score = wredf(sc);
  if (l == 0) {
    score += tstart[b * CC + target[b]] +
             tend[b * CC + target[(len - 1) * BB + b]];
    atomicAdd(out, (logz - score) * (1.0f / 256.0f));
  }
}

extern "C" void kernel_launch(void* const* d_in, const int* in_sizes, int n_in,
                              void* d_out, int out_size, void* d_ws, size_t ws_size,
                              hipStream_t stream) {
  const float* emit = (const float*)d_in[0];
  const float* hidden = (const float*)d_in[1];
  const int* target = (const int*)d_in[2];
  const void* mask = d_in[3];
  const float* Wt = (const float*)d_in[4];
  const float* bt = (const float*)d_in[5];
  const float* Ws = (const float*)d_in[6];
  const float* bs = (const float*)d_in[7];
  const float* We = (const float*)d_in[8];
  const float* be = (const float*)d_in[9];

  float* trans_ws = (float*)d_ws;                  // 256*9216
  float* ts_ws = trans_ws + (size_t)BB * CC * CC;  // 256*96
  float* te_ws = ts_ws + (size_t)BB * CC;          // 256*96
  float* xvec = te_ws + (size_t)BB * CC;           // 3840*96
  float* lsc = xvec + (size_t)BB * CHPB * CC;      // 3840

  hipMemsetAsync(d_out, 0, sizeof(float), stream);

  gemm_mfma<<<dim3((NTOT + 127) / 128, 2), 256, 0, stream>>>(
      hidden, Wt, Ws, We, bt, bs, be, trans_ws, ts_ws, te_ws);

  crf_chain<<<BB * 8, 64, 0, stream>>>(emit, mask, trans_ws, ts_ws, xvec, lsc);

  crf_compose<<<BB, 64, 0, stream>>>(emit, target, mask, trans_ws, ts_ws, te_ws,
                                     xvec, lsc, (float*)d_out);
}